// Round 10
// baseline (677.660 us; speedup 1.0000x reference)
//
#include <hip/hip_runtime.h>
#include <stdint.h>

// B=8, N=4096, D=256, F=1024.  MFMA 16x16x32 bf16.
// R9 (measured): total 634us; aggs now VALU-bound on bit-unpack
//   (enh 178us, MfmaUtil 16%, VALUBusy 78%).  Gram unsplit OK (absmax 0.03125).
// R10: aggregation GEMMs widened to 128x256 tiles, 512 threads (8 waves 2Mx4N)
//   -> 2x MFMA per unpacked bit, enh A-bits unpacked once (single j-block).

typedef unsigned short u16;
typedef __attribute__((ext_vector_type(8))) short bf16x8;
typedef __attribute__((ext_vector_type(4))) float f32x4;

#define GLDS(g, l) __builtin_amdgcn_global_load_lds((const __attribute__((address_space(1))) void*)(g), (__attribute__((address_space(3))) void*)(l), 16, 0, 0)

__device__ __forceinline__ float4 ld4(const float* p){ return *reinterpret_cast<const float4*>(p); }
__device__ __forceinline__ u16 f2bf(float f){
    union{float f;unsigned u;}x{f};
    unsigned r=(x.u+0x7FFFu+((x.u>>16)&1u))>>16; return (u16)r;
}
__device__ __forceinline__ float bf2f(u16 s){
    union{unsigned u;float f;}x{(unsigned)s<<16}; return x.f;
}
__device__ __forceinline__ unsigned pk2(unsigned v, int i){
    return (((v>>i)&1u)*0x3F80u) | (((v>>(i+1))&1u)*0x3F800000u);
}

// ---------------------------------------------------------------------------
// mg: 128x128 tile, 256 threads (4 waves).  Used for gram / XT / FFN.
// LDS tile [128 rows][4 chunks of 8 u16]; phys chunk = logical ^ ((row>>1)&3).
// ---------------------------------------------------------------------------
template<int EPI, bool SPLIT, bool ABITS, bool BBITS>
__global__ __launch_bounds__(256)
void mg(const u16* __restrict__ A, const u16* __restrict__ A2,
        const u16* __restrict__ Bt, const u16* __restrict__ B2,
        void* __restrict__ C, void* __restrict__ C2,
        int K, int lda, int ldb, int ldc,
        long long sA, long long sB, long long sC, long long sC2,
        const float* __restrict__ bias,
        const float* __restrict__ v1, long long sv1,
        const float* __restrict__ v2, long long sv2,
        const void* __restrict__ resid, long long sR)
{
    __shared__ u16 As[4096], Bs[4096];
    __shared__ u16 As2[SPLIT ? 4096 : 8], Bs2[SPLIT ? 4096 : 8];
    const int t = threadIdx.x, lane = t & 63, wv = t >> 6;
    const int i0 = blockIdx.x*128, j0 = blockIdx.y*128, z = blockIdx.z;
    const int wr = (wv>>1)*64, wc = (wv&1)*64;

    const u16* Az  = A  + (size_t)z*sA;
    const u16* Bz  = Bt + (size_t)z*sB;
    const u16* A2z = SPLIT ? A2 + (size_t)z*sA : nullptr;
    const u16* B2z = SPLIT ? B2 + (size_t)z*sB : nullptr;

    const int glr = lane >> 2;
    const int gsc = (lane & 3) ^ ((glr >> 1) & 3);
    const int frow = lane & 15;
    const int fcho = ((lane >> 4) ^ ((frow >> 1) & 3)) * 8;

    f32x4 zero4 = {0.f,0.f,0.f,0.f};
    f32x4 acc[4][4];
    #pragma unroll
    for (int m=0;m<4;++m)
        #pragma unroll
        for (int n=0;n<4;++n) acc[m][n] = zero4;

    for (int k0 = 0; k0 < K; k0 += 32) {
        if constexpr (ABITS) {
            const int row = t & 127, half = t >> 7, sw = (row>>1)&3;
            unsigned v = Az[(size_t)(i0+row)*lda + (k0>>4) + half];
            u16* base = As + row*32;
            uint4 w0, w1;
            w0.x=pk2(v,0);  w0.y=pk2(v,2);  w0.z=pk2(v,4);  w0.w=pk2(v,6);
            w1.x=pk2(v,8);  w1.y=pk2(v,10); w1.z=pk2(v,12); w1.w=pk2(v,14);
            *(uint4*)(base + ((2*half  )^sw)*8) = w0;
            *(uint4*)(base + ((2*half+1)^sw)*8) = w1;
        } else {
            #pragma unroll
            for (int q=0;q<2;++q) {
                const int lr = wv*32 + q*16 + glr;
                GLDS(Az + (size_t)(i0+lr)*lda + k0 + gsc*8, As + (wv*32 + q*16)*32);
            }
        }
        if constexpr (BBITS) {
            const int row = t & 127, half = t >> 7, sw = (row>>1)&3;
            unsigned v = Bz[(size_t)(j0+row)*ldb + (k0>>4) + half];
            u16* base = Bs + row*32;
            uint4 w0, w1;
            w0.x=pk2(v,0);  w0.y=pk2(v,2);  w0.z=pk2(v,4);  w0.w=pk2(v,6);
            w1.x=pk2(v,8);  w1.y=pk2(v,10); w1.z=pk2(v,12); w1.w=pk2(v,14);
            *(uint4*)(base + ((2*half  )^sw)*8) = w0;
            *(uint4*)(base + ((2*half+1)^sw)*8) = w1;
        } else {
            #pragma unroll
            for (int q=0;q<2;++q) {
                const int lr = wv*32 + q*16 + glr;
                GLDS(Bz + (size_t)(j0+lr)*ldb + k0 + gsc*8, Bs + (wv*32 + q*16)*32);
            }
        }
        if constexpr (SPLIT) {
            #pragma unroll
            for (int q=0;q<2;++q) {
                const int lr = wv*32 + q*16 + glr;
                GLDS(A2z + (size_t)(i0+lr)*lda + k0 + gsc*8, As2 + (wv*32 + q*16)*32);
                GLDS(B2z + (size_t)(j0+lr)*ldb + k0 + gsc*8, Bs2 + (wv*32 + q*16)*32);
            }
        }
        __syncthreads();

        bf16x8 fa[4], fb[4];
        #pragma unroll
        for (int m=0;m<4;++m) fa[m] = *(const bf16x8*)&As[(wr + m*16 + frow)*32 + fcho];
        #pragma unroll
        for (int n=0;n<4;++n) fb[n] = *(const bf16x8*)&Bs[(wc + n*16 + frow)*32 + fcho];
        if constexpr (SPLIT) {
            bf16x8 fa2[4], fb2[4];
            #pragma unroll
            for (int m=0;m<4;++m) fa2[m] = *(const bf16x8*)&As2[(wr + m*16 + frow)*32 + fcho];
            #pragma unroll
            for (int n=0;n<4;++n) fb2[n] = *(const bf16x8*)&Bs2[(wc + n*16 + frow)*32 + fcho];
            #pragma unroll
            for (int m=0;m<4;++m)
                #pragma unroll
                for (int n=0;n<4;++n) {
                    acc[m][n] = __builtin_amdgcn_mfma_f32_16x16x32_bf16(fa[m],  fb[n],  acc[m][n], 0,0,0);
                    acc[m][n] = __builtin_amdgcn_mfma_f32_16x16x32_bf16(fa[m],  fb2[n], acc[m][n], 0,0,0);
                    acc[m][n] = __builtin_amdgcn_mfma_f32_16x16x32_bf16(fa2[m], fb[n],  acc[m][n], 0,0,0);
                }
        } else {
            #pragma unroll
            for (int m=0;m<4;++m)
                #pragma unroll
                for (int n=0;n<4;++n)
                    acc[m][n] = __builtin_amdgcn_mfma_f32_16x16x32_bf16(fa[m], fb[n], acc[m][n], 0,0,0);
        }
        __syncthreads();
    }

    const int cl = lane & 15, rg = lane >> 4;
    if constexpr (EPI == 1) {
        u16* hgb  = (u16*)C  + (size_t)z*sC;
        u16* hgtb = (u16*)C2 + (size_t)z*sC2;
        const float* v1z = v1 + (size_t)z*sv1;
        const float* v2z = v2 + (size_t)z*sv2;
        #pragma unroll
        for (int m=0;m<4;++m) {
            #pragma unroll
            for (int n=0;n<4;++n) {
                const int rb = i0 + wr + m*16;
                const int cb = j0 + wc + n*16;
                const float n2c = v2z[cb + cl];
                unsigned long long b0,b1,b2,b3;
                { float s = v1z[rb+rg*4+0] + n2c - 2.f*acc[m][n][0]; b0 = __ballot(s < 529.f); }
                { float s = v1z[rb+rg*4+1] + n2c - 2.f*acc[m][n][1]; b1 = __ballot(s < 529.f); }
                { float s = v1z[rb+rg*4+2] + n2c - 2.f*acc[m][n][2]; b2 = __ballot(s < 529.f); }
                { float s = v1z[rb+rg*4+3] + n2c - 2.f*acc[m][n][3]; b3 = __ballot(s < 529.f); }
                unsigned long long bsel = (cl&2) ? ((cl&1)? b3 : b2) : ((cl&1)? b1 : b0);
                if (cl < 4)
                    hgb[(size_t)(rb + rg*4 + cl)*ldc + (cb>>4)] = (u16)((bsel >> (rg*16)) & 0xFFFFull);
                if (rg == 0) {
                    unsigned tb = 0;
                    #pragma unroll
                    for (int k=0;k<16;++k) {
                        unsigned long long bb = (k&2) ? ((k&1)? b3:b2) : ((k&1)? b1:b0);
                        tb |= (unsigned)((bb >> ((k>>2)*16 + cl)) & 1ull) << k;
                    }
                    hgtb[(size_t)(cb + cl)*ldc + (rb>>4)] = (u16)tb;
                }
            }
        }
    } else {
        float* Cf  = (float*)C  + (size_t)z*sC;
        u16*   Cb  = (u16*)C    + (size_t)z*sC;
        const float* Rf = (const float*)resid + (size_t)z*sR;
        #pragma unroll
        for (int m=0;m<4;++m) {
            #pragma unroll
            for (int n=0;n<4;++n) {
                const int cc = j0 + wc + n*16 + cl;
                #pragma unroll
                for (int j=0;j<4;++j) {
                    const int r = i0 + wr + m*16 + rg*4 + j;
                    const float v = acc[m][n][j];
                    if constexpr (EPI == 0) {
                        Cb[(size_t)r*ldc + cc] = f2bf(v + bias[r]);
                    } else if constexpr (EPI == 4) {
                        float o = v + bias[cc];
                        Cb[(size_t)r*ldc + cc] = f2bf(o > 0.f ? o : 0.f);
                    } else {
                        Cf[(size_t)r*ldc + cc] = v + bias[cc] + Rf[(size_t)r*ldc + cc];
                    }
                }
            }
        }
    }
}

// ---------------------------------------------------------------------------
// ag: aggregation GEMM, 128x256 tile, 512 threads (8 waves = 2M x 4N).
// EPI==2 (ET): A = XTb bf16 (GLDS), B = hgtb BITS.  C_bf = acc/deg[col] + bf(resid)
// EPI==3 (enh): A = hgb BITS, B = ETb bf16 (GLDS).  Cf = acc/deg[row] + Rf; C2_bf
// LDS: As[128][32] u16 (8KB), Bs[256][32] u16 (16KB); chunk-XOR swizzle.
// ---------------------------------------------------------------------------
template<int EPI>
__global__ __launch_bounds__(512)
void ag(const u16* __restrict__ A, const u16* __restrict__ Bt,
        void* __restrict__ C, void* __restrict__ C2,
        int K, int lda, int ldb, int ldc,
        long long sA, long long sB, long long sC, long long sC2,
        const float* __restrict__ deg, long long sdeg,
        const void* __restrict__ resid, long long sR)
{
    __shared__ u16 As[4096];
    __shared__ u16 Bs[8192];
    const int t = threadIdx.x, lane = t & 63, wv = t >> 6;      // 8 waves
    const int i0 = blockIdx.x*128, j0 = blockIdx.y*256, z = blockIdx.z;
    const int wr = (wv>>2)*64, wc = (wv&3)*64;

    const u16* Az = A  + (size_t)z*sA;
    const u16* Bz = Bt + (size_t)z*sB;

    const int glr = lane >> 2;
    const int gsc = (lane & 3) ^ ((glr >> 1) & 3);
    const int frow = lane & 15;
    const int fcho = ((lane >> 4) ^ ((frow >> 1) & 3)) * 8;

    f32x4 zero4 = {0.f,0.f,0.f,0.f};
    f32x4 acc[4][4];
    #pragma unroll
    for (int m=0;m<4;++m)
        #pragma unroll
        for (int n=0;n<4;++n) acc[m][n] = zero4;

    for (int k0 = 0; k0 < K; k0 += 32) {
        // ---- A tile: 128 rows x 32 k
        if constexpr (EPI == 3) {
            // bits: thread t -> row r = t&127, quarter q = t>>7 (8 bits -> 8 bf16)
            const int r = t & 127, q = t >> 7, sw = (r>>1)&3;
            unsigned v32 = *(const unsigned*)(Az + (size_t)(i0+r)*lda + (k0>>4));
            unsigned b = (v32 >> (q*8)) & 0xFFu;
            uint4 w;
            w.x = pk2(b,0); w.y = pk2(b,2); w.z = pk2(b,4); w.w = pk2(b,6);
            *(uint4*)(As + r*32 + (q ^ sw)*8) = w;
        } else {
            // bf16 GLDS: 8 waves x 16 rows = 128 rows, one call
            GLDS(Az + (size_t)(i0 + wv*16 + glr)*lda + k0 + gsc*8, As + (wv*16)*32);
        }
        // ---- B tile: 256 rows x 32 k
        if constexpr (EPI == 2) {
            // bits: thread t -> row r = t&255, half h = t>>8 (16 bits -> 16 bf16)
            const int r = t & 255, h = t >> 8, sw = (r>>1)&3;
            unsigned v = Bz[(size_t)(j0+r)*ldb + (k0>>4) + h];
            u16* base = Bs + r*32;
            uint4 w0, w1;
            w0.x=pk2(v,0);  w0.y=pk2(v,2);  w0.z=pk2(v,4);  w0.w=pk2(v,6);
            w1.x=pk2(v,8);  w1.y=pk2(v,10); w1.z=pk2(v,12); w1.w=pk2(v,14);
            *(uint4*)(base + ((2*h  )^sw)*8) = w0;
            *(uint4*)(base + ((2*h+1)^sw)*8) = w1;
        } else {
            // bf16 GLDS: 2 rounds x (8 waves x 16 rows) = 256 rows
            #pragma unroll
            for (int q=0;q<2;++q) {
                const int rb = q*128 + wv*16;
                GLDS(Bz + (size_t)(j0 + rb + glr)*ldb + k0 + gsc*8, Bs + rb*32);
            }
        }
        __syncthreads();

        bf16x8 fa[4], fb[4];
        #pragma unroll
        for (int m=0;m<4;++m) fa[m] = *(const bf16x8*)&As[(wr + m*16 + frow)*32 + fcho];
        #pragma unroll
        for (int n=0;n<4;++n) fb[n] = *(const bf16x8*)&Bs[(wc + n*16 + frow)*32 + fcho];
        #pragma unroll
        for (int m=0;m<4;++m)
            #pragma unroll
            for (int n=0;n<4;++n)
                acc[m][n] = __builtin_amdgcn_mfma_f32_16x16x32_bf16(fa[m], fb[n], acc[m][n], 0,0,0);
        __syncthreads();
    }

    const int cl = lane & 15, rg = lane >> 4;
    const float* degz = deg + (size_t)z*sdeg;
    if constexpr (EPI == 2) {
        u16* Cb = (u16*)C + (size_t)z*sC;
        const u16* Rb = (const u16*)resid + (size_t)z*sR;
        #pragma unroll
        for (int m=0;m<4;++m) {
            #pragma unroll
            for (int n=0;n<4;++n) {
                const int cc = j0 + wc + n*16 + cl;
                float d = degz[cc]; float nm = d > 0.f ? 1.f/d : 0.f;
                #pragma unroll
                for (int j=0;j<4;++j) {
                    const int r = i0 + wr + m*16 + rg*4 + j;
                    Cb[(size_t)r*ldc + cc] = f2bf(acc[m][n][j]*nm + bf2f(Rb[(size_t)r*ldc + cc]));
                }
            }
        }
    } else {
        float* Cf  = (float*)C  + (size_t)z*sC;
        u16*   C2b = (u16*)C2   + (size_t)z*sC2;
        const float* Rf = (const float*)resid + (size_t)z*sR;
        #pragma unroll
        for (int m=0;m<4;++m) {
            #pragma unroll
            for (int n=0;n<4;++n) {
                const int cc = j0 + wc + n*16 + cl;
                #pragma unroll
                for (int j=0;j<4;++j) {
                    const int r = i0 + wr + m*16 + rg*4 + j;
                    float d = degz[r]; float nm = d > 0.f ? 1.f/d : 0.f;
                    float o = acc[m][n][j]*nm + Rf[(size_t)r*ldc + cc];
                    Cf [(size_t)r*ldc + cc] = o;
                    C2b[(size_t)r*ldc + cc] = f2bf(o);
                }
            }
        }
    }
}

// ---- fused prep: bf16 convert of ind & disc + row squared-norms ------------
__global__ __launch_bounds__(256)
void prep_k(const float* __restrict__ ind, const float* __restrict__ disc,
            u16* __restrict__ ih, u16* __restrict__ dh,
            float* __restrict__ n1, float* __restrict__ n2, int rows)
{
    int wid = threadIdx.x >> 6, lane = threadIdx.x & 63;
    int r = blockIdx.x*4 + wid;
    const float* src; u16 *hi; float* dst; int rr;
    if (r < rows) { src = ind;  hi = ih; dst = n1; rr = r; }
    else          { src = disc; hi = dh; dst = n2; rr = r - rows; }
    size_t off = (size_t)rr*256 + lane*4;
    float4 v = ld4(src + off);
    ushort4 h;
    h.x = f2bf(v.x); h.y = f2bf(v.y); h.z = f2bf(v.z); h.w = f2bf(v.w);
    *(ushort4*)(hi+off) = h;
    float s = v.x*v.x + v.y*v.y + v.z*v.z + v.w*v.w;
    #pragma unroll
    for (int o=32;o;o>>=1) s += __shfl_down(s, o);
    if (lane == 0) dst[rr] = s;
}

// ---- weight bf16 conversion -----------------------------------------------
__global__ __launch_bounds__(256)
void cvtw_k(const float* __restrict__ wfc, const float* __restrict__ w1,
            const float* __restrict__ w2, u16* __restrict__ owfc,
            u16* __restrict__ ow1, u16* __restrict__ ow2)
{
    int i = blockIdx.x*256 + threadIdx.x;
    if (i < 65536)  owfc[i] = f2bf(wfc[i]);
    if (i < 262144) { ow1[i] = f2bf(w1[i]); ow2[i] = f2bf(w2[i]); }
}

// ---- disc [b][n][d] f32 -> discT [b][d][n] bf16 ---------------------------
__global__ __launch_bounds__(256)
void tr_k(const float* __restrict__ src, u16* __restrict__ dst)
{
    __shared__ float tl[64][65];
    const int b = blockIdx.z, n0 = blockIdx.x*64, d0 = blockIdx.y*64;
    const float* s = src + (size_t)b*1048576;
    u16* o = dst + (size_t)b*1048576;
    const int tx = threadIdx.x & 15, ty = threadIdx.x >> 4;
    #pragma unroll
    for (int it=0; it<4; ++it) {
        int r = ty + it*16;
        float4 v = ld4(s + (size_t)(n0+r)*256 + d0 + tx*4);
        tl[r][tx*4+0]=v.x; tl[r][tx*4+1]=v.y; tl[r][tx*4+2]=v.z; tl[r][tx*4+3]=v.w;
    }
    __syncthreads();
    #pragma unroll
    for (int it=0; it<4; ++it) {
        int d = ty + it*16;
        ushort4 w;
        w.x = f2bf(tl[tx*4+0][d]); w.y = f2bf(tl[tx*4+1][d]);
        w.z = f2bf(tl[tx*4+2][d]); w.w = f2bf(tl[tx*4+3][d]);
        *(ushort4*)(o + (size_t)(d0+d)*4096 + n0 + tx*4) = w;
    }
}

// ---- degree = popcount of a bit-row ---------------------------------------
__global__ __launch_bounds__(256)
void popc_k(const u16* __restrict__ bits, float* __restrict__ deg)
{
    int wv = threadIdx.x >> 6, lane = threadIdx.x & 63;
    size_t row = (size_t)blockIdx.x*4 + wv;
    const unsigned* p = (const unsigned*)(bits + row*256);
    int s = __popc(p[lane]) + __popc(p[lane+64]);
    #pragma unroll
    for (int o=32;o;o>>=1) s += __shfl_down(s, o);
    if (lane == 0) deg[row] = (float)s;
}

// ---- LayerNorm over D=256 -------------------------------------------------
__global__ __launch_bounds__(256)
void ln_k(const float* __restrict__ q, const float* __restrict__ g,
          const float* __restrict__ bta, float* __restrict__ out)
{
    size_t row = blockIdx.x;
    int t = threadIdx.x;
    float x = q[row*256 + t];
    float s1 = x, s2 = x*x;
    int lane = t & 63, wid = t >> 6;
    #pragma unroll
    for (int o=32;o;o>>=1) { s1 += __shfl_down(s1,o); s2 += __shfl_down(s2,o); }
    __shared__ float a1[4], a2[4];
    if (lane == 0) { a1[wid]=s1; a2[wid]=s2; }
    __syncthreads();
    s1 = a1[0]+a1[1]+a1[2]+a1[3];
    s2 = a2[0]+a2[1]+a2[2]+a2[3];
    float mu  = s1 * (1.f/256.f);
    float var = s2 * (1.f/256.f) - mu*mu;
    float r = rsqrtf(var + 1e-5f);
    out[row*256 + t] = (x - mu) * r * g[t] + bta[t];
}

extern "C" void kernel_launch(void* const* d_in, const int* in_sizes, int n_in,
                              void* d_out, int out_size, void* d_ws, size_t ws_size,
                              hipStream_t stream)
{
    const float* disc = (const float*)d_in[0];
    const float* ind  = (const float*)d_in[1];
    const float* W_fc = (const float*)d_in[2];
    const float* b_fc = (const float*)d_in[3];
    const float* W1   = (const float*)d_in[4];
    const float* b1   = (const float*)d_in[5];
    const float* W2   = (const float*)d_in[6];
    const float* b2   = (const float*)d_in[7];
    const float* ln_g = (const float*)d_in[8];
    const float* ln_b = (const float*)d_in[9];
    float* out = (float*)d_out;

    char* ws = (char*)d_ws;
    u16* hgb   = (u16*)(ws + 0);           // hg  bits [b][n][256ch]   16.78MB
    u16* hgtb  = (u16*)(ws + 16777216);    // hgT bits [b][e][256ch]   16.78MB
    u16* ETb   = (u16*)(ws + 33554432);    // E^T bf16 [b][256][4096]  16.78MB
    u16* ih    = (u16*)(ws + 50331648);    // ind bf16                 16.78MB
    u16* dh    = (u16*)(ws + 83886080);    // disc bf16                16.78MB
    u16* discT = (u16*)(ws + 117440512);
    u16* XTb   = (u16*)(ws + 134217728);
    float* enhF= (float*)(ws + 150994944); // enh f32 [BN][256]        33.55MB
    u16* enhB  = (u16*)(ws + 184549376);
    u16* wfcb  = (u16*)(ws + 201326592);
    u16* w1b   = (u16*)(ws + 201457664);
    u16* w2b   = (u16*)(ws + 201981952);
    float* n1  = (float*)(ws + 202506240);
    float* n2  = (float*)(ws + 202637312);
    float* dN  = (float*)(ws + 202768384);
    float* dE  = (float*)(ws + 202899456);
    u16* hB    = (u16*)(ws + 83886080);    // h bf16 aliases dh..XTb (dead)
    float* qF  = (float*)(ws + 50331648);  // q f32 aliases ih + free slot (dead)

    const int BN = 32768;
    const long long S = 1048576;

    prep_k<<<16384, 256, 0, stream>>>(ind, disc, ih, dh, n1, n2, BN);
    cvtw_k<<<1024, 256, 0, stream>>>(W_fc, W1, W2, wfcb, w1b, w2b);
    tr_k<<<dim3(64,4,8), 256, 0, stream>>>(disc, discT);

    // gram (pure bf16): hg = bit-packed both orientations
    mg<1,false,false,false><<<dim3(32,32,8), 256, 0, stream>>>(
        ih, nullptr, dh, nullptr, hgb, hgtb, 256, 256, 256, 256,
        S, S, S, S, nullptr, n1, 4096, n2, 4096, nullptr, 0);

    popc_k<<<8192, 256, 0, stream>>>(hgb,  dN);
    popc_k<<<8192, 256, 0, stream>>>(hgtb, dE);

    // XT[b][c][n] = sum_d W_fc[c,d]*ind[b,n,d] + b_fc[c]
    mg<0,false,false,false><<<dim3(2,32,8), 256, 0, stream>>>(
        wfcb, nullptr, ih, nullptr, XTb, nullptr, 256, 256, 256, 4096,
        0, S, S, 0, b_fc, nullptr, 0, nullptr, 0, nullptr, 0);

    // ET[b][c][e] = (sum_n XT[c][n]*hgT[e][n]) / degE[e] + discT[c][e]
    ag<2><<<dim3(2,16,8), 512, 0, stream>>>(
        XTb, hgtb, ETb, nullptr, 4096, 4096, 256, 4096,
        S, S, S, 0, dE, 4096, discT, S);

    // enh = (sum_e hg[n][e]*ET[c][e]) / degN[n] + ind   (f32 + bf16)
    ag<3><<<dim3(32,1,8), 512, 0, stream>>>(
        hgb, ETb, enhF, enhB, 4096, 256, 4096, 256,
        S, S, S, S, dN, 4096, ind, S);

    // h = relu(enh @ W1^T + b1)
    mg<4,false,false,false><<<dim3(256,8,1), 256, 0, stream>>>(
        enhB, nullptr, w1b, nullptr, hB, nullptr, 256, 256, 256, 1024,
        0, 0, 0, 0, b1, nullptr, 0, nullptr, 0, nullptr, 0);

    // q = h @ W2^T + b2 + enh   (f32)
    mg<5,false,false,false><<<dim3(256,2,1), 256, 0, stream>>>(
        hB, nullptr, w2b, nullptr, qF, nullptr, 1024, 1024, 1024, 256,
        0, 0, 0, 0, b2, nullptr, 0, nullptr, 0, enhF, 0);

    ln_k<<<BN, 256, 0, stream>>>(qF, ln_g, ln_b, out);
}